// Round 11
// baseline (337.330 us; speedup 1.0000x reference)
//
#include <hip/hip_runtime.h>
#include <cstdint>
#include <cstddef>

#define BATCH   4
#define SEQ     4096
#define HIDDEN  4096
#define RANK    512
#define OUTF    4096
#define SROWS   4097              // seq+1
#define MROWS   (BATCH * SROWS)   // 16388

typedef int v4i __attribute__((ext_vector_type(4)));

#define AS1 __attribute__((address_space(1)))
#define AS3 __attribute__((address_space(3)))

// ---------------------------------------------------------------------------
// Kernel 1: new_latent[b][r] = dot(new_x[b,0,:], B_weight[r,:])
// ---------------------------------------------------------------------------
__global__ void k_new_latent(const float* __restrict__ newx,
                             const float* __restrict__ Bw,
                             float* __restrict__ out_latent) {
    int wave = threadIdx.x >> 6;
    int lane = threadIdx.x & 63;
    int pair = blockIdx.x * 4 + wave;   // 0..2047
    int b = pair >> 9;
    int r = pair & 511;
    const float4* x4 = (const float4*)(newx + (size_t)b * HIDDEN);
    const float4* w4 = (const float4*)(Bw + (size_t)r * HIDDEN);
    float sum = 0.f;
#pragma unroll
    for (int j = 0; j < 16; ++j) {
        float4 xv = x4[lane + 64 * j];
        float4 wv = w4[lane + 64 * j];
        sum += xv.x * wv.x + xv.y * wv.y + xv.z * wv.z + xv.w * wv.w;
    }
#pragma unroll
    for (int off = 32; off >= 1; off >>= 1)
        sum += __shfl_xor(sum, off, 64);
    if (lane == 0) {
        out_latent[(size_t)(b * SROWS + SEQ) * RANK + r] = sum;
    }
}

// ---------------------------------------------------------------------------
// Kernel 2: per-row int8 quant (rank=512) + copy cached rows to output.
// ---------------------------------------------------------------------------
__global__ void k_quant(const float* __restrict__ cached,
                        float* __restrict__ out_latent,
                        int8_t* __restrict__ Qq,
                        float* __restrict__ scales) {
    int m = blockIdx.x * 4 + (threadIdx.x >> 6);   // 0..16387
    int lane = threadIdx.x & 63;
    int b = m / SROWS;
    int s = m - b * SROWS;
    const float* src = (s < SEQ) ? (cached + ((size_t)b * SEQ + s) * RANK)
                                 : (out_latent + (size_t)m * RANK);
    float4 v0 = ((const float4*)src)[lane];
    float4 v1 = ((const float4*)src)[64 + lane];
    float am = fmaxf(fmaxf(fmaxf(fabsf(v0.x), fabsf(v0.y)),
                           fmaxf(fabsf(v0.z), fabsf(v0.w))),
                     fmaxf(fmaxf(fabsf(v1.x), fabsf(v1.y)),
                           fmaxf(fabsf(v1.z), fabsf(v1.w))));
#pragma unroll
    for (int off = 32; off >= 1; off >>= 1)
        am = fmaxf(am, __shfl_xor(am, off, 64));
    am = fmaxf(am, 1e-8f);
    float scale = am / 127.0f;

    auto qp = [&](float x) -> uint32_t {
        float r = rintf(x / scale);          // round-half-even, matches jnp.round
        r = fminf(fmaxf(r, -128.0f), 127.0f);
        return (uint32_t)(uint8_t)(int8_t)(int)r;
    };
    uint32_t p0 = qp(v0.x) | (qp(v0.y) << 8) | (qp(v0.z) << 16) | (qp(v0.w) << 24);
    uint32_t p1 = qp(v1.x) | (qp(v1.y) << 8) | (qp(v1.z) << 16) | (qp(v1.w) << 24);
    uint32_t* qrow = (uint32_t*)(Qq + (size_t)m * RANK);
    qrow[lane] = p0;
    qrow[64 + lane] = p1;
    if (s < SEQ) {
        float4* dst = (float4*)(out_latent + (size_t)m * RANK);
        dst[lane] = v0;
        dst[64 + lane] = v1;
    }
    if (lane == 0) scales[m] = scale;
}

// ---------------------------------------------------------------------------
// Kernel 3: pack A_int8 (int32 storage, 4096x512) -> int8 bytes.
// ---------------------------------------------------------------------------
__global__ void k_packA(const int* __restrict__ Ai, uint8_t* __restrict__ Ap) {
    int idx = blockIdx.x * blockDim.x + threadIdx.x;
    int4 v = ((const int4*)Ai)[idx];
    uint32_t p = (uint32_t)(v.x & 0xff) | ((uint32_t)(v.y & 0xff) << 8) |
                 ((uint32_t)(v.z & 0xff) << 16) | ((uint32_t)(v.w & 0xff) << 24);
    ((uint32_t*)Ap)[idx] = p;
}

// ---------------------------------------------------------------------------
// Kernel 4: int8 GEMM + dequant — R9 geometry (best so far, 134.2 total).
// BM=128, BN=64, BK=64, 4 waves (2Mx2N), acc = 8 v4i = 32 VGPR, dbuf LDS,
// counted vmcnt(3), pair-XOR swizzle, XCD-bijective block swizzle.
//
// MEASUREMENT ROUND: kernel_launch runs this GEMM 3x (idempotent — writes
// only out[0..MROWS*OUTF), never reads it). T_warm = (total - 134.2)/2
// isolates steady-state GEMM time with warm/clean Qq, discriminating
// internal-stall vs cold/dirty-L2 first-touch theories.
// ---------------------------------------------------------------------------
#define BM 128
#define BN 64
#define BK 64
#define NT_N (OUTF / BN)   // 64
#define NKT  (RANK / BK)   // 8

__launch_bounds__(256, 6)
__global__ void k_gemm(const int8_t* __restrict__ Qq,
                       const int8_t* __restrict__ Ap,
                       const float* __restrict__ scales,
                       const float* __restrict__ Ascale,
                       float* __restrict__ out,
                       int M) {
    __shared__ __align__(16) int8_t Qs[2][BM * BK];   // 2 x 8 KiB
    __shared__ __align__(16) int8_t As[2][BN * BK];   // 2 x 4 KiB

    // XCD-bijective blockIdx swizzle (gridDim.x = 8256, % 8 == 0), tn-minor.
    int per = gridDim.x >> 3;
    int bid = blockIdx.x;
    int swz = (bid & 7) * per + (bid >> 3);
    int tn = swz & (NT_N - 1);
    int tm = swz >> 6;          // / NT_N

    int tid = threadIdx.x;
    int lane = tid & 63;
    int wave = tid >> 6;
    int wr = wave >> 1, wc = wave & 1;
    int m0 = tm * BM;
    int n0 = tn * BN;

    int R0 = tid >> 2;
    int cg = (tid & 3) ^ ((tid >> 3) & 3);
    int grow0 = m0 + R0;       if (grow0 >= M) grow0 = M - 1;
    int grow1 = m0 + R0 + 64;  if (grow1 >= M) grow1 = M - 1;
    const int8_t* q0 = Qq + (size_t)grow0 * RANK + cg * 16;
    const int8_t* q1 = Qq + (size_t)grow1 * RANK + cg * 16;
    const int8_t* a0 = Ap + (size_t)(n0 + R0) * RANK + cg * 16;
    uint32_t wb = (uint32_t)(wave * 1024);   // wave-uniform LDS byte base

#define STAGE(bufi, kt) do {                                                  \
    int off_ = (kt) * BK;                                                     \
    __builtin_amdgcn_global_load_lds((const AS1 uint32_t*)(q0 + off_),        \
        (AS3 uint32_t*)(&Qs[bufi][0] + wb), 16, 0, 0);                        \
    __builtin_amdgcn_global_load_lds((const AS1 uint32_t*)(q1 + off_),        \
        (AS3 uint32_t*)(&Qs[bufi][0] + wb + 4096), 16, 0, 0);                 \
    __builtin_amdgcn_global_load_lds((const AS1 uint32_t*)(a0 + off_),        \
        (AS3 uint32_t*)(&As[bufi][0] + wb), 16, 0, 0);                        \
  } while (0)

    v4i acc[4][2] = {};
    int g = lane >> 4;                 // K-quarter
    int rl = lane & 15;
    int sl = g ^ ((rl >> 1) & 3);      // swizzled LDS chunk slot

    STAGE(0, 0);
#pragma unroll
    for (int kt = 0; kt < NKT; ++kt) {
        int cb = kt & 1;
        if (kt < NKT - 1) {
            STAGE(cb ^ 1, kt + 1);
            asm volatile("s_waitcnt vmcnt(3)" ::: "memory");
        } else {
            asm volatile("s_waitcnt vmcnt(0)" ::: "memory");
        }
        __builtin_amdgcn_s_barrier();   // tile kt fully in LDS

        v4i aF[4], bF[2];
#pragma unroll
        for (int mi = 0; mi < 4; ++mi) {
            int row = wr * 64 + mi * 16 + rl;
            aF[mi] = *(const v4i*)(&Qs[cb][0] + row * BK + sl * 16);
        }
#pragma unroll
        for (int ni = 0; ni < 2; ++ni) {
            int row = wc * 32 + ni * 16 + rl;
            bF[ni] = *(const v4i*)(&As[cb][0] + row * BK + sl * 16);
        }
#pragma unroll
        for (int mi = 0; mi < 4; ++mi)
#pragma unroll
            for (int ni = 0; ni < 2; ++ni)
                acc[mi][ni] = __builtin_amdgcn_mfma_i32_16x16x64_i8(
                    aF[mi], bF[ni], acc[mi][ni], 0, 0, 0);

        __builtin_amdgcn_s_barrier();   // reads done before next overwrite
    }
#undef STAGE

    // Epilogue: dequant + store. C/D: col = lane&15, row = (lane>>4)*4+r.
    int gq = lane >> 4;
    int cn = lane & 15;
#pragma unroll
    for (int mi = 0; mi < 4; ++mi) {
        int mbase = m0 + wr * 64 + mi * 16 + gq * 4;
        float sm[4];
#pragma unroll
        for (int r = 0; r < 4; ++r) {
            int mm = mbase + r;
            sm[r] = (mm < M) ? scales[mm] : 0.f;
        }
#pragma unroll
        for (int ni = 0; ni < 2; ++ni) {
            int n = n0 + wc * 32 + ni * 16 + cn;
            float asc = Ascale[n];
#pragma unroll
            for (int r = 0; r < 4; ++r) {
                int mm = mbase + r;
                if (mm < M)
                    out[(size_t)mm * OUTF + n] = (float)acc[mi][ni][r] * sm[r] * asc;
            }
        }
    }
}

// ---------------------------------------------------------------------------
extern "C" void kernel_launch(void* const* d_in, const int* in_sizes, int n_in,
                              void* d_out, int out_size, void* d_ws, size_t ws_size,
                              hipStream_t stream) {
    const float* new_x  = (const float*)d_in[0];
    const float* cached = (const float*)d_in[1];
    const float* Bw     = (const float*)d_in[2];
    const int*   Ai     = (const int*)d_in[3];
    const float* Ascale = (const float*)d_in[4];

    float* out = (float*)d_out;
    float* out_latent = out + (size_t)MROWS * OUTF;

    const size_t Q_BYTES = (size_t)MROWS * RANK;
    const size_t S_BYTES = (size_t)MROWS * sizeof(float);
    int8_t*  Qq     = (int8_t*)d_ws;
    float*   scales = (float*)((char*)d_ws + Q_BYTES);
    int8_t*  Ap     = (int8_t*)((char*)d_ws + Q_BYTES + S_BYTES);

    k_new_latent<<<512, 256, 0, stream>>>(new_x, Bw, out_latent);
    k_quant<<<SROWS, 256, 0, stream>>>(cached, out_latent, Qq, scales);
    k_packA<<<(OUTF * RANK / 4) / 256, 256, 0, stream>>>(Ai, (uint8_t*)Ap);
    int nt_m = (MROWS + BM - 1) / BM;   // 129
    // MEASUREMENT: 3x identical GEMM launches (idempotent). Launch 1 = cold
    // (Qq dirty in producer XCDs' L2); launches 2,3 = warm steady state.
    // T_warm = (total_dur - 134.2us) / 2.
    k_gemm<<<nt_m * NT_N, 256, 0, stream>>>(Qq, Ap, scales, Ascale, out, MROWS);
    k_gemm<<<nt_m * NT_N, 256, 0, stream>>>(Qq, Ap, scales, Ascale, out, MROWS);
    k_gemm<<<nt_m * NT_N, 256, 0, stream>>>(Qq, Ap, scales, Ascale, out, MROWS);
}

// Round 12
// 133.372 us; speedup vs baseline: 2.5292x; 2.5292x over previous
//
#include <hip/hip_runtime.h>
#include <cstdint>
#include <cstddef>

#define BATCH   4
#define SEQ     4096
#define HIDDEN  4096
#define RANK    512
#define OUTF    4096
#define SROWS   4097              // seq+1
#define MROWS   (BATCH * SROWS)   // 16388
#define NGRP    1025              // ceil(MROWS/16) groups in packed Q

typedef int v4i __attribute__((ext_vector_type(4)));

// Packed fragment-major layout for int8 operands:
//   T[G][kc][r] = 16 bytes, addr = G*8192 + kc*256 + r*16
//   (G = row>>4, r = row&15, kc = 16-byte K-chunk index 0..31)
// A wave's MFMA fragment for K-step kt (64 B = chunks 4kt..4kt+3) is the
// contiguous 1 KB at G*8192 + kt*1024, lane l -> (row l&15, quarter l>>4):
// exactly the mfma_i32_16x16x64_i8 operand mapping proven in R2-R11.

// ---------------------------------------------------------------------------
// Kernel 1: new_latent[b][r] = dot(new_x[b,0,:], B_weight[r,:])
// ---------------------------------------------------------------------------
__global__ void k_new_latent(const float* __restrict__ newx,
                             const float* __restrict__ Bw,
                             float* __restrict__ out_latent) {
    int wave = threadIdx.x >> 6;
    int lane = threadIdx.x & 63;
    int pair = blockIdx.x * 4 + wave;   // 0..2047
    int b = pair >> 9;
    int r = pair & 511;
    const float4* x4 = (const float4*)(newx + (size_t)b * HIDDEN);
    const float4* w4 = (const float4*)(Bw + (size_t)r * HIDDEN);
    float sum = 0.f;
#pragma unroll
    for (int j = 0; j < 16; ++j) {
        float4 xv = x4[lane + 64 * j];
        float4 wv = w4[lane + 64 * j];
        sum += xv.x * wv.x + xv.y * wv.y + xv.z * wv.z + xv.w * wv.w;
    }
#pragma unroll
    for (int off = 32; off >= 1; off >>= 1)
        sum += __shfl_xor(sum, off, 64);
    if (lane == 0) {
        out_latent[(size_t)(b * SROWS + SEQ) * RANK + r] = sum;
    }
}

// ---------------------------------------------------------------------------
// Kernel 2: per-row int8 quant + copy cached rows to output; writes Qt in
// packed fragment-major layout. One wave per row.
// Lane l holds cols 4l..4l+3 (p0) and 256+4l..259+4l (p1):
//   p0 -> kc = l>>2, byte (l&3)*4  => addr0 = G*8192 + (l>>2)*256 + r*16 + (l&3)*4
//   p1 -> kc = 16 + (l>>2)         => addr0 + 4096
// ---------------------------------------------------------------------------
__global__ void k_quant(const float* __restrict__ cached,
                        float* __restrict__ out_latent,
                        uint8_t* __restrict__ Qt,
                        float* __restrict__ scales) {
    int m = blockIdx.x * 4 + (threadIdx.x >> 6);   // 0..16387
    int lane = threadIdx.x & 63;
    int b = m / SROWS;
    int s = m - b * SROWS;
    const float* src = (s < SEQ) ? (cached + ((size_t)b * SEQ + s) * RANK)
                                 : (out_latent + (size_t)m * RANK);
    float4 v0 = ((const float4*)src)[lane];
    float4 v1 = ((const float4*)src)[64 + lane];
    float am = fmaxf(fmaxf(fmaxf(fabsf(v0.x), fabsf(v0.y)),
                           fmaxf(fabsf(v0.z), fabsf(v0.w))),
                     fmaxf(fmaxf(fabsf(v1.x), fabsf(v1.y)),
                           fmaxf(fabsf(v1.z), fabsf(v1.w))));
#pragma unroll
    for (int off = 32; off >= 1; off >>= 1)
        am = fmaxf(am, __shfl_xor(am, off, 64));
    am = fmaxf(am, 1e-8f);
    float scale = am / 127.0f;

    auto qp = [&](float x) -> uint32_t {
        float r = rintf(x / scale);          // round-half-even, matches jnp.round
        r = fminf(fmaxf(r, -128.0f), 127.0f);
        return (uint32_t)(uint8_t)(int8_t)(int)r;
    };
    uint32_t p0 = qp(v0.x) | (qp(v0.y) << 8) | (qp(v0.z) << 16) | (qp(v0.w) << 24);
    uint32_t p1 = qp(v1.x) | (qp(v1.y) << 8) | (qp(v1.z) << 16) | (qp(v1.w) << 24);

    int G = m >> 4, r = m & 15;
    uint32_t addr0 = (uint32_t)(G * 8192 + ((lane >> 2) << 8) + r * 16 + (lane & 3) * 4);
    *(uint32_t*)(Qt + addr0) = p0;
    *(uint32_t*)(Qt + addr0 + 4096) = p1;

    if (s < SEQ) {
        float4* dst = (float4*)(out_latent + (size_t)m * RANK);
        dst[lane] = v0;
        dst[64 + lane] = v1;
    }
    if (lane == 0) scales[m] = scale;
}

// ---------------------------------------------------------------------------
// Kernel 3: pack A_int8 (int32, 4096x512) -> packed fragment-major int8.
// Thread t: row n = t>>7, quad q = t&127 (cols 4q..4q+3).
// ---------------------------------------------------------------------------
__global__ void k_packA(const int* __restrict__ Ai, uint8_t* __restrict__ At) {
    int t = blockIdx.x * blockDim.x + threadIdx.x;   // 0..524287
    int n = t >> 7;
    int q = t & 127;
    int4 v = ((const int4*)(Ai + (size_t)n * RANK))[q];
    uint32_t p = (uint32_t)(v.x & 0xff) | ((uint32_t)(v.y & 0xff) << 8) |
                 ((uint32_t)(v.z & 0xff) << 16) | ((uint32_t)(v.w & 0xff) << 24);
    int G = n >> 4, r = n & 15;
    uint32_t addr = (uint32_t)(G * 8192 + ((q >> 2) << 8) + r * 16 + (q & 3) * 4);
    *(uint32_t*)(At + addr) = p;
}

// ---------------------------------------------------------------------------
// Kernel 4: int8 GEMM + dequant — PACKED DIRECT-REG. No LDS, no barriers.
// BM=128, BN=64, 4 waves (2Mx2N), each wave 64x32. Per K-step: 6 fully
// contiguous 1-KB wave loads (4 aF + 2 bF) + 8 MFMA, explicit 2-deep
// register double-buffer (full unroll -> constant indices, no scratch).
// Waves fully independent -> pure TLP latency hiding (16 waves/CU).
// ---------------------------------------------------------------------------
#define BM 128
#define BN 64
#define NT_N (OUTF / BN)   // 64
#define NKT  8

__launch_bounds__(256, 4)
__global__ void k_gemm(const uint8_t* __restrict__ Qt,
                       const uint8_t* __restrict__ At,
                       const float* __restrict__ scales,
                       const float* __restrict__ Ascale,
                       float* __restrict__ out,
                       int M) {
    // XCD-bijective blockIdx swizzle (gridDim.x = 8256, % 8 == 0), tn-minor:
    // co-XCD blocks share the Q-panel and sweep At together in L2.
    int per = gridDim.x >> 3;
    int bid = blockIdx.x;
    int swz = (bid & 7) * per + (bid >> 3);
    int tn = swz & (NT_N - 1);
    int tm = swz >> 6;          // / NT_N

    int tid = threadIdx.x;
    int lane = tid & 63;
    int wave = tid >> 6;
    int wr = wave >> 1, wc = wave & 1;
    int m0 = tm * BM;
    int n0 = tn * BN;

    uint32_t l16 = (uint32_t)lane * 16;
    const uint8_t* ap[4];
    const uint8_t* bp[2];
#pragma unroll
    for (int mi = 0; mi < 4; ++mi) {
        int G = (m0 + wr * 64 + mi * 16) >> 4;
        if (G >= NGRP) G = NGRP - 1;           // tail clamp (store-masked)
        ap[mi] = Qt + (uint32_t)G * 8192 + l16;
    }
#pragma unroll
    for (int ni = 0; ni < 2; ++ni) {
        int H = (n0 + wc * 32 + ni * 16) >> 4;
        bp[ni] = At + (uint32_t)H * 8192 + l16;
    }

    v4i aF[2][4], bF[2][2];
#pragma unroll
    for (int x = 0; x < 4; ++x) aF[0][x] = *(const v4i*)(ap[x]);
#pragma unroll
    for (int x = 0; x < 2; ++x) bF[0][x] = *(const v4i*)(bp[x]);

    v4i acc[4][2] = {};
#pragma unroll
    for (int kt = 0; kt < NKT; ++kt) {
        const int cur = kt & 1;          // constant after unroll
        if (kt < NKT - 1) {
            const uint32_t off = (uint32_t)(kt + 1) * 1024;
#pragma unroll
            for (int x = 0; x < 4; ++x) aF[cur ^ 1][x] = *(const v4i*)(ap[x] + off);
#pragma unroll
            for (int x = 0; x < 2; ++x) bF[cur ^ 1][x] = *(const v4i*)(bp[x] + off);
        }
#pragma unroll
        for (int mi = 0; mi < 4; ++mi)
#pragma unroll
            for (int ni = 0; ni < 2; ++ni)
                acc[mi][ni] = __builtin_amdgcn_mfma_i32_16x16x64_i8(
                    aF[cur][mi], bF[cur][ni], acc[mi][ni], 0, 0, 0);
    }

    // Epilogue: dequant + store. C/D: col = lane&15, row = (lane>>4)*4+r.
    int gq = lane >> 4;
    int cn = lane & 15;
#pragma unroll
    for (int mi = 0; mi < 4; ++mi) {
        int mbase = m0 + wr * 64 + mi * 16 + gq * 4;
        float sm[4];
#pragma unroll
        for (int r = 0; r < 4; ++r) {
            int mm = mbase + r;
            sm[r] = (mm < M) ? scales[mm] : 0.f;
        }
#pragma unroll
        for (int ni = 0; ni < 2; ++ni) {
            int n = n0 + wc * 32 + ni * 16 + cn;
            float asc = Ascale[n];
#pragma unroll
            for (int r = 0; r < 4; ++r) {
                int mm = mbase + r;
                if (mm < M)
                    out[(size_t)mm * OUTF + n] = (float)acc[mi][ni][r] * sm[r] * asc;
            }
        }
    }
}

// ---------------------------------------------------------------------------
extern "C" void kernel_launch(void* const* d_in, const int* in_sizes, int n_in,
                              void* d_out, int out_size, void* d_ws, size_t ws_size,
                              hipStream_t stream) {
    const float* new_x  = (const float*)d_in[0];
    const float* cached = (const float*)d_in[1];
    const float* Bw     = (const float*)d_in[2];
    const int*   Ai     = (const int*)d_in[3];
    const float* Ascale = (const float*)d_in[4];

    float* out = (float*)d_out;
    float* out_latent = out + (size_t)MROWS * OUTF;

    const size_t QT_BYTES = (size_t)NGRP * 8192;        // 8,396,800
    const size_t S_BYTES  = (size_t)MROWS * sizeof(float);
    uint8_t* Qt     = (uint8_t*)d_ws;
    float*   scales = (float*)((char*)d_ws + QT_BYTES);
    uint8_t* At     = (uint8_t*)((char*)d_ws + QT_BYTES + S_BYTES);

    k_new_latent<<<512, 256, 0, stream>>>(new_x, Bw, out_latent);
    k_quant<<<SROWS, 256, 0, stream>>>(cached, out_latent, Qt, scales);
    k_packA<<<(OUTF * RANK / 4) / 256, 256, 0, stream>>>(Ai, At);
    int nt_m = (MROWS + BM - 1) / BM;   // 129
    k_gemm<<<nt_m * NT_N, 256, 0, stream>>>(Qt, At, scales, Ascale, out, MROWS);
}

// Round 14
// 114.727 us; speedup vs baseline: 2.9403x; 1.1625x over previous
//
#include <hip/hip_runtime.h>
#include <cstdint>
#include <cstddef>

#define BATCH   4
#define SEQ     4096
#define HIDDEN  4096
#define RANK    512
#define OUTF    4096
#define SROWS   4097              // seq+1
#define MROWS   (BATCH * SROWS)   // 16388
#define NGRP    1025              // ceil(MROWS/16) groups in packed Q

typedef int v4i __attribute__((ext_vector_type(4)));
typedef float v4f __attribute__((ext_vector_type(4)));

// Packed fragment-major layout for int8 operands:
//   T[G][kc][r] = 16 bytes, addr = G*8192 + kc*256 + r*16
//   (G = row>>4, r = row&15, kc = 16-byte K-chunk index 0..31)
// A wave's MFMA fragment for K-step kt is the contiguous 1 KB at
// G*8192 + kt*1024, lane l -> (row l&15, quarter l>>4).

// ---------------------------------------------------------------------------
// Kernel 1: new_latent[b][r] = dot(new_x[b,0,:], B_weight[r,:])
// ---------------------------------------------------------------------------
__global__ void k_new_latent(const float* __restrict__ newx,
                             const float* __restrict__ Bw,
                             float* __restrict__ out_latent) {
    int wave = threadIdx.x >> 6;
    int lane = threadIdx.x & 63;
    int pair = blockIdx.x * 4 + wave;   // 0..2047
    int b = pair >> 9;
    int r = pair & 511;
    const float4* x4 = (const float4*)(newx + (size_t)b * HIDDEN);
    const float4* w4 = (const float4*)(Bw + (size_t)r * HIDDEN);
    float sum = 0.f;
#pragma unroll
    for (int j = 0; j < 16; ++j) {
        float4 xv = x4[lane + 64 * j];
        float4 wv = w4[lane + 64 * j];
        sum += xv.x * wv.x + xv.y * wv.y + xv.z * wv.z + xv.w * wv.w;
    }
#pragma unroll
    for (int off = 32; off >= 1; off >>= 1)
        sum += __shfl_xor(sum, off, 64);
    if (lane == 0) {
        out_latent[(size_t)(b * SROWS + SEQ) * RANK + r] = sum;
    }
}

// ---------------------------------------------------------------------------
// Kernel 2: per-row int8 quant + copy cached rows to output; writes Qt in
// packed fragment-major layout. One wave per row.
// out_latent copy is NON-TEMPORAL (streamed once, never re-read) to keep
// it from polluting L2. Qt/scales stay cached (consumed by k_gemm).
// ---------------------------------------------------------------------------
__global__ void k_quant(const float* __restrict__ cached,
                        float* __restrict__ out_latent,
                        uint8_t* __restrict__ Qt,
                        float* __restrict__ scales) {
    int m = blockIdx.x * 4 + (threadIdx.x >> 6);   // 0..16387
    int lane = threadIdx.x & 63;
    int b = m / SROWS;
    int s = m - b * SROWS;
    const float* src = (s < SEQ) ? (cached + ((size_t)b * SEQ + s) * RANK)
                                 : (out_latent + (size_t)m * RANK);
    float4 v0 = ((const float4*)src)[lane];
    float4 v1 = ((const float4*)src)[64 + lane];
    float am = fmaxf(fmaxf(fmaxf(fabsf(v0.x), fabsf(v0.y)),
                           fmaxf(fabsf(v0.z), fabsf(v0.w))),
                     fmaxf(fmaxf(fabsf(v1.x), fabsf(v1.y)),
                           fmaxf(fabsf(v1.z), fabsf(v1.w))));
#pragma unroll
    for (int off = 32; off >= 1; off >>= 1)
        am = fmaxf(am, __shfl_xor(am, off, 64));
    am = fmaxf(am, 1e-8f);
    float scale = am / 127.0f;

    auto qp = [&](float x) -> uint32_t {
        float r = rintf(x / scale);          // round-half-even, matches jnp.round
        r = fminf(fmaxf(r, -128.0f), 127.0f);
        return (uint32_t)(uint8_t)(int8_t)(int)r;
    };
    uint32_t p0 = qp(v0.x) | (qp(v0.y) << 8) | (qp(v0.z) << 16) | (qp(v0.w) << 24);
    uint32_t p1 = qp(v1.x) | (qp(v1.y) << 8) | (qp(v1.z) << 16) | (qp(v1.w) << 24);

    int G = m >> 4, r = m & 15;
    uint32_t addr0 = (uint32_t)(G * 8192 + ((lane >> 2) << 8) + r * 16 + (lane & 3) * 4);
    *(uint32_t*)(Qt + addr0) = p0;
    *(uint32_t*)(Qt + addr0 + 4096) = p1;

    if (s < SEQ) {
        v4f* dst = (v4f*)(out_latent + (size_t)m * RANK);
        v4f w0 = { v0.x, v0.y, v0.z, v0.w };
        v4f w1 = { v1.x, v1.y, v1.z, v1.w };
        __builtin_nontemporal_store(w0, &dst[lane]);
        __builtin_nontemporal_store(w1, &dst[64 + lane]);
    }
    if (lane == 0) scales[m] = scale;
}

// ---------------------------------------------------------------------------
// Kernel 3: pack A_int8 (int32, 4096x512) -> packed fragment-major int8.
// ---------------------------------------------------------------------------
__global__ void k_packA(const int* __restrict__ Ai, uint8_t* __restrict__ At) {
    int t = blockIdx.x * blockDim.x + threadIdx.x;   // 0..524287
    int n = t >> 7;
    int q = t & 127;
    int4 v = ((const int4*)(Ai + (size_t)n * RANK))[q];
    uint32_t p = (uint32_t)(v.x & 0xff) | ((uint32_t)(v.y & 0xff) << 8) |
                 ((uint32_t)(v.z & 0xff) << 16) | ((uint32_t)(v.w & 0xff) << 24);
    int G = n >> 4, r = n & 15;
    uint32_t addr = (uint32_t)(G * 8192 + ((q >> 2) << 8) + r * 16 + (q & 3) * 4);
    *(uint32_t*)(At + addr) = p;
}

// ---------------------------------------------------------------------------
// Kernel 4: int8 GEMM + dequant — PACKED DIRECT-REG (R12) + NON-TEMPORAL
// output stores. Theory: 268 MB of cached stores sweep the 32-MB L2 8x,
// evicting the operand panels (R4 PMC: FETCH=72.5 MB for 10.4 MB operands
// = ~8x refetch) -> chronic L2/L3-miss latency that defeated every schedule.
// nt stores stream past L2, keeping Qt/At resident.
// ---------------------------------------------------------------------------
#define BM 128
#define BN 64
#define NT_N (OUTF / BN)   // 64
#define NKT  8

__launch_bounds__(256, 4)
__global__ void k_gemm(const uint8_t* __restrict__ Qt,
                       const uint8_t* __restrict__ At,
                       const float* __restrict__ scales,
                       const float* __restrict__ Ascale,
                       float* __restrict__ out,
                       int M) {
    // XCD-bijective blockIdx swizzle (gridDim.x = 8256, % 8 == 0), tn-minor.
    int per = gridDim.x >> 3;
    int bid = blockIdx.x;
    int swz = (bid & 7) * per + (bid >> 3);
    int tn = swz & (NT_N - 1);
    int tm = swz >> 6;          // / NT_N

    int tid = threadIdx.x;
    int lane = tid & 63;
    int wave = tid >> 6;
    int wr = wave >> 1, wc = wave & 1;
    int m0 = tm * BM;
    int n0 = tn * BN;

    uint32_t l16 = (uint32_t)lane * 16;
    const uint8_t* ap[4];
    const uint8_t* bp[2];
#pragma unroll
    for (int mi = 0; mi < 4; ++mi) {
        int G = (m0 + wr * 64 + mi * 16) >> 4;
        if (G >= NGRP) G = NGRP - 1;           // tail clamp (store-masked)
        ap[mi] = Qt + (uint32_t)G * 8192 + l16;
    }
#pragma unroll
    for (int ni = 0; ni < 2; ++ni) {
        int H = (n0 + wc * 32 + ni * 16) >> 4;
        bp[ni] = At + (uint32_t)H * 8192 + l16;
    }

    v4i aF[2][4], bF[2][2];
#pragma unroll
    for (int x = 0; x < 4; ++x) aF[0][x] = *(const v4i*)(ap[x]);
#pragma unroll
    for (int x = 0; x < 2; ++x) bF[0][x] = *(const v4i*)(bp[x]);

    v4i acc[4][2] = {};
#pragma unroll
    for (int kt = 0; kt < NKT; ++kt) {
        const int cur = kt & 1;          // constant after unroll
        if (kt < NKT - 1) {
            const uint32_t off = (uint32_t)(kt + 1) * 1024;
#pragma unroll
            for (int x = 0; x < 4; ++x) aF[cur ^ 1][x] = *(const v4i*)(ap[x] + off);
#pragma unroll
            for (int x = 0; x < 2; ++x) bF[cur ^ 1][x] = *(const v4i*)(bp[x] + off);
        }
#pragma unroll
        for (int mi = 0; mi < 4; ++mi)
#pragma unroll
            for (int ni = 0; ni < 2; ++ni)
                acc[mi][ni] = __builtin_amdgcn_mfma_i32_16x16x64_i8(
                    aF[cur][mi], bF[cur][ni], acc[mi][ni], 0, 0, 0);
    }

    // Epilogue: dequant + NON-TEMPORAL store.
    // C/D: col = lane&15, row = (lane>>4)*4+r.
    int gq = lane >> 4;
    int cn = lane & 15;
#pragma unroll
    for (int mi = 0; mi < 4; ++mi) {
        int mbase = m0 + wr * 64 + mi * 16 + gq * 4;
        float sm[4];
#pragma unroll
        for (int r = 0; r < 4; ++r) {
            int mm = mbase + r;
            sm[r] = (mm < M) ? scales[mm] : 0.f;
        }
#pragma unroll
        for (int ni = 0; ni < 2; ++ni) {
            int n = n0 + wc * 32 + ni * 16 + cn;
            float asc = Ascale[n];
#pragma unroll
            for (int r = 0; r < 4; ++r) {
                int mm = mbase + r;
                if (mm < M) {
                    float v = (float)acc[mi][ni][r] * sm[r] * asc;
                    __builtin_nontemporal_store(v, &out[(size_t)mm * OUTF + n]);
                }
            }
        }
    }
}

// ---------------------------------------------------------------------------
extern "C" void kernel_launch(void* const* d_in, const int* in_sizes, int n_in,
                              void* d_out, int out_size, void* d_ws, size_t ws_size,
                              hipStream_t stream) {
    const float* new_x  = (const float*)d_in[0];
    const float* cached = (const float*)d_in[1];
    const float* Bw     = (const float*)d_in[2];
    const int*   Ai     = (const int*)d_in[3];
    const float* Ascale = (const float*)d_in[4];

    float* out = (float*)d_out;
    float* out_latent = out + (size_t)MROWS * OUTF;

    const size_t QT_BYTES = (size_t)NGRP * 8192;        // 8,396,800
    const size_t S_BYTES  = (size_t)MROWS * sizeof(float);
    uint8_t* Qt     = (uint8_t*)d_ws;
    float*   scales = (float*)((char*)d_ws + QT_BYTES);
    uint8_t* At     = (uint8_t*)((char*)d_ws + QT_BYTES + S_BYTES);

    k_new_latent<<<512, 256, 0, stream>>>(new_x, Bw, out_latent);
    k_quant<<<SROWS, 256, 0, stream>>>(cached, out_latent, Qt, scales);
    k_packA<<<(OUTF * RANK / 4) / 256, 256, 0, stream>>>(Ai, At);
    int nt_m = (MROWS + BM - 1) / BM;   // 129
    k_gemm<<<nt_m * NT_N, 256, 0, stream>>>(Qt, At, scales, Ascale, out, MROWS);
}